// Round 9
// baseline (412.626 us; speedup 1.0000x reference)
//
#include <hip/hip_runtime.h>
#include <hip/hip_bf16.h>

#define M_SAMPLES 524288
#define NRAYS 8192
#define GXD 160
#define GYD 160
#define GZD 128
#define GYZ (GYD*GZD)
#define NVOX (GXD*GYD*GZD)
#define ACT_SHIFT -13.81550955796f
#define SAMP 64       // samples per k_mlp block

// LDS activation layout: sample s -> row R=s&31 (512B rows), half H=s>>5 (byte bit 8),
// logical byte c in [0,256) per half; stored at R*512 + ((H<<8 | c) ^ ((R&31)<<4)).
// XOR swizzle is bijective on bits 4..8 -> MFMA ds_read_b128 2-way (free),
// epilogue 8B writes conflict-free, posemb scalar writes 2-way.

typedef __bf16 bf16x8 __attribute__((ext_vector_type(8)));
typedef float f32x4 __attribute__((ext_vector_type(4)));
typedef float f32x16 __attribute__((ext_vector_type(16)));
typedef float f32v2 __attribute__((ext_vector_type(2)));
typedef __fp16 f16x2 __attribute__((ext_vector_type(2)));

static __device__ inline unsigned short f2bf(float f){
  __hip_bfloat16 h = __float2bfloat16(f);
  unsigned short u; __builtin_memcpy(&u, &h, 2); return u;
}
static __device__ inline float flo(unsigned int u){ return __uint_as_float(u << 16); }
static __device__ inline float fhi(unsigned int u){ return __uint_as_float(u & 0xffff0000u); }

#if defined(__has_builtin)
#if __has_builtin(__builtin_amdgcn_cvt_pk_bf16_f32)
#define HAVE_PK_BF16 1
#endif
#if __has_builtin(__builtin_amdgcn_cvt_pk_f32_fp8) && __has_builtin(__builtin_amdgcn_cvt_pk_fp8_f32)
#define HAVE_FP8 1
#endif
#endif

static __device__ inline unsigned int packbf(float a, float b){
#ifdef HAVE_PK_BF16
  typedef __bf16 bf16v2 __attribute__((ext_vector_type(2)));
  bf16v2 r = __builtin_amdgcn_cvt_pk_bf16_f32(a, b);
  unsigned int u; __builtin_memcpy(&u, &r, 4); return u;
#else
  return (unsigned int)f2bf(a) | ((unsigned int)f2bf(b) << 16);
#endif
}

struct Tri {
  int ix, iy, iz;
  float wx0, wx1, wy0, wy1, wz0, wz1;
};
static __device__ inline Tri tri_setup(float x, float y, float z){
  Tri t;
  float tx = (x+1.f)*0.5f*(float)(GXD-1); tx = fminf(fmaxf(tx,0.f),(float)(GXD-1));
  float ty = (y+1.f)*0.5f*(float)(GYD-1); ty = fminf(fmaxf(ty,0.f),(float)(GYD-1));
  float tz = (z+1.f)*0.5f*(float)(GZD-1); tz = fminf(fmaxf(tz,0.f),(float)(GZD-1));
  t.ix = min((int)tx, GXD-2); t.iy = min((int)ty, GYD-2); t.iz = min((int)tz, GZD-2);
  float fx = tx-t.ix, fy = ty-t.iy, fz = tz-t.iz;
  t.wx0 = 1.f-fx; t.wx1 = fx; t.wy0 = 1.f-fy; t.wy1 = fy; t.wz0 = 1.f-fz; t.wz1 = fz;
  return t;
}

// ---------------- merged prologue: repack | detect | weights | ray view-term ---
#define NB_REPACK (NVOX/256)              // 12800
#define NB_W      184                     // ceil(47104/256)
#define NB_RT     (NRAYS/256)             // 32
__global__ __launch_bounds__(256) void k_prep(
    const float* __restrict__ density, const float* __restrict__ k0,
    uint4* __restrict__ packed,
    const unsigned int* __restrict__ mw, int* __restrict__ flag,
    const float* __restrict__ W0, const float* __restrict__ W1,
    const float* __restrict__ W2, const float* __restrict__ Wr,
    const float* __restrict__ br,
    unsigned short* __restrict__ wt0, unsigned short* __restrict__ wt1,
    unsigned short* __restrict__ wt2, unsigned short* __restrict__ wtr,
    const float* __restrict__ vd, float* __restrict__ rayterm3)
{
  int b = blockIdx.x;
  if(b < NB_REPACK){
    int v = b*256 + threadIdx.x;
    const float4* kp = (const float4*)(k0 + (size_t)v*12);
    float4 a = kp[0], bb = kp[1], c = kp[2];
#ifdef HAVE_FP8
    uint4 o;
    o.x = __float_as_uint(density[v]);
    int w;
    w = __builtin_amdgcn_cvt_pk_fp8_f32(a.x, a.y, 0, false);
    w = __builtin_amdgcn_cvt_pk_fp8_f32(a.z, a.w, w, true);
    o.y = (unsigned int)w;
    w = __builtin_amdgcn_cvt_pk_fp8_f32(bb.x, bb.y, 0, false);
    w = __builtin_amdgcn_cvt_pk_fp8_f32(bb.z, bb.w, w, true);
    o.z = (unsigned int)w;
    w = __builtin_amdgcn_cvt_pk_fp8_f32(c.x, c.y, 0, false);
    w = __builtin_amdgcn_cvt_pk_fp8_f32(c.z, c.w, w, true);
    o.w = (unsigned int)w;
    packed[v] = o;
#else
    uint4 o0, o1;
    o0.x = __float_as_uint(density[v]);
    o0.y = packbf(a.x, a.y); o0.z = packbf(a.z, a.w); o0.w = packbf(bb.x, bb.y);
    o1.x = packbf(bb.z, bb.w); o1.y = packbf(c.x, c.y); o1.z = packbf(c.z, c.w);
    o1.w = 0;
    packed[(size_t)v*2]   = o0;
    packed[(size_t)v*2+1] = o1;
#endif
    return;
  }
  if(b == NB_REPACK){
    unsigned int v = mw[threadIdx.x & 63];
    unsigned long long any = __ballot(v > 1u);
    if(threadIdx.x == 0) *flag = (any != 0ull) ? 1 : 0;   // 1 = byte mask
    return;
  }
  if(b < NB_REPACK + 1 + NB_W){
    int t = (b - NB_REPACK - 1)*256 + threadIdx.x;
    if(t < 128*96){
      int n = t/96, k = t%96;
      wt0[t] = f2bf((k < 75) ? W0[k*128 + n] : 0.f);
    } else if(t < 128*96 + 16384){
      int j = t - 128*96; int n = j/128, k = j%128;
      wt1[j] = f2bf(W1[k*128 + n]);
    } else if(t < 128*96 + 32768){
      int j = t - 128*96 - 16384; int n = j/128, k = j%128;
      wt2[j] = f2bf(W2[k*128 + n]);
    } else if(t < 128*96 + 32768 + 16*128){
      int j = t - 128*96 - 32768; int n = j/128, k = j%128;
      wtr[j] = f2bf((n < 3) ? Wr[k*3 + n] : 0.f);
    }
    return;
  }
  // per-ray view term: rayterm3[ray][c] = br[c] + sum_j ve_j * Wr[(128+j)*3+c]
  int ray = (b - NB_REPACK - 1 - NB_W)*256 + threadIdx.x;
  if(ray >= NRAYS) return;
  float v0 = vd[ray*3+0], v1 = vd[ray*3+1], v2 = vd[ray*3+2];
  float vej[27];
  vej[0] = v0; vej[1] = v1; vej[2] = v2;
  #pragma unroll
  for(int ci = 0; ci < 3; ++ci){
    float xv = (ci == 0) ? v0 : ((ci == 1) ? v1 : v2);
    #pragma unroll
    for(int p = 0; p < 4; ++p){
      float arg = xv * (float)(1 << p);
      vej[3 + ci*4 + p]  = __sinf(arg);
      vej[15 + ci*4 + p] = __cosf(arg);
    }
  }
  float rt0 = br[0], rt1 = br[1], rt2 = br[2];
  #pragma unroll
  for(int j = 0; j < 27; ++j){
    const float* wr = Wr + (128 + j)*3;
    rt0 += vej[j]*wr[0]; rt1 += vej[j]*wr[1]; rt2 += vej[j]*wr[2];
  }
  rayterm3[ray*3+0] = rt0; rayterm3[ray*3+1] = rt1; rayterm3[ray*3+2] = rt2;
}

// ---------------- MFMA layer: swizzled LDS reads, bias in acc init -------------
template<int KDIM>
static __device__ __forceinline__ void mfma_layer(const unsigned short* src,
    const bf16x8* wf, const float* __restrict__ bias, int tile_n,
    f32x16& acc0, f32x16& acc1, int ln, int kh)
{
  constexpr int NS = KDIM/16;
  const char* s8 = (const char*)src;
  int lnx = ln << 4;
  int rowb = ln * 512;
  #pragma unroll
  for(int g = 0; g < 4; ++g){
    float4 bv = *(const float4*)(bias + tile_n*32 + g*8 + kh*4);
    acc0[4*g+0] = bv.x; acc0[4*g+1] = bv.y; acc0[4*g+2] = bv.z; acc0[4*g+3] = bv.w;
  }
  acc1 = acc0;
  __builtin_amdgcn_s_setprio(1);
  #pragma unroll
  for(int st = 0; st < NS; ++st){
    bf16x8 a0 = *(const bf16x8*)(s8 + rowb + ((         (kh<<4) | (st<<5)) ^ lnx));
    bf16x8 a1 = *(const bf16x8*)(s8 + rowb + (((1<<8) | (kh<<4) | (st<<5)) ^ lnx));
    acc0 = __builtin_amdgcn_mfma_f32_32x32x16_bf16(wf[st], a0, acc0, 0, 0, 0);
    acc1 = __builtin_amdgcn_mfma_f32_32x32x16_bf16(wf[st], a1, acc1, 0, 0, 0);
  }
  __builtin_amdgcn_s_setprio(0);
}

template<int NS>
static __device__ __forceinline__ void load_wf(const unsigned short* wbase, bf16x8* wf){
  #pragma unroll
  for(int st = 0; st < NS; ++st) wf[st] = *(const bf16x8*)(wbase + st*16);
}

// epilogue: ReLU + bf16 pack -> swizzled LDS (bias already in acc)
static __device__ __forceinline__ void epilogue(const f32x16& acc0, const f32x16& acc1,
    unsigned short* dst, int tile_n, int ln, int kh)
{
  char* d8 = (char*)dst;
  int lnx = ln << 4;
  int rowb = ln * 512;
  #pragma unroll
  for(int rep = 0; rep < 2; ++rep){
    const f32x16& acc = rep ? acc1 : acc0;
    #pragma unroll
    for(int g = 0; g < 4; ++g){
      unsigned int lo = packbf(fmaxf(acc[4*g+0], 0.f), fmaxf(acc[4*g+1], 0.f));
      unsigned int hi = packbf(fmaxf(acc[4*g+2], 0.f), fmaxf(acc[4*g+3], 0.f));
      unsigned long long o = (unsigned long long)lo | ((unsigned long long)hi << 32);
      int cb = ((rep<<8) | (tile_n<<6) | (g<<4) | (kh<<3)) ^ lnx;
      *(unsigned long long*)(d8 + rowb + cb) = o;
    }
  }
}

// ---------------- fused: gather+alpha + posemb + MLP + head -> per-sample rgba -
template<int PACKED>
__global__ __launch_bounds__(256, 4) void k_mlp(const float* __restrict__ xyz,
    const uint4* __restrict__ packed,
    const float* __restrict__ density, const float* __restrict__ k0,
    const void* __restrict__ mask, const int* __restrict__ flag,
    const int* __restrict__ ray_id,
    const unsigned short* __restrict__ wt0, const unsigned short* __restrict__ wt1,
    const unsigned short* __restrict__ wt2, const unsigned short* __restrict__ wtr,
    const float* __restrict__ b0, const float* __restrict__ b1,
    const float* __restrict__ b2,
    const float* __restrict__ rayterm3, float4* __restrict__ rgba_out)
{
  __shared__ alignas(16) unsigned short hA[32*256];   // 16KB, swizzled
  __shared__ alignas(16) unsigned short hB[32*256];   // 16KB, swizzled
  __shared__ float red[SAMP][4];
  __shared__ int ray_s[SAMP];

  int tid = threadIdx.x;
  int lane = tid & 63, wave = tid >> 6;
  int blk = blockIdx.x*SAMP;
  int ln = lane & 31, kh = lane >> 5;

  // layer-0 weight prefetch at entry: latency hides under phase 0
  bf16x8 wf[8];
  load_wf<6>(wt0 + (wave*32 + ln)*96 + kh*8, wf);

  // ---- phase 0a: gather. 256 lanes = 64 samples x 4 corners (dz in-thread) --
  {
    int smp = tid >> 2, corner = tid & 3;
    int i = blk + smp;
    float x = xyz[3*i+0], y = xyz[3*i+1], z = xyz[3*i+2];
    Tri t = tri_setup(x, y, z);
    int dx = corner & 1, dy = corner >> 1;
    float wxy = (dx ? t.wx1 : t.wx0) * (dy ? t.wy1 : t.wy0);
    float w0 = wxy*t.wz0, w1 = wxy*t.wz1;
    size_t vox = (size_t)((t.ix+dx)*GYZ + (t.iy+dy)*GZD + t.iz);

    // hoisted scattered loads (all corners; same addr per sample -> broadcast):
    // their latency overlaps the voxel loads instead of the post-butterfly tail
    int mx = (int)rintf(x*79.5f + 79.5f); mx = min(max(mx,0), GXD-1);
    int my = (int)rintf(y*79.5f + 79.5f); my = min(max(my,0), GYD-1);
    int mz = (int)rintf(z*63.5f + 63.5f); mz = min(max(mz,0), GZD-1);
    int midx = mx*GYZ + my*GZD + mz;
    int flg = *flag;
    unsigned int mv = flg ? (unsigned int)(((const unsigned char*)mask)[midx])
                          : ((const unsigned int*)mask)[midx];
    int rid = ray_id[i];

    float pd;
    float pf[12];
#ifdef HAVE_FP8
    if(PACKED){
      uint4 q0 = packed[vox], q1 = packed[vox+1];
      pd = w0*__uint_as_float(q0.x) + w1*__uint_as_float(q1.x);
      f32v2 a, b;
      a = __builtin_amdgcn_cvt_pk_f32_fp8((int)q0.y, false);
      b = __builtin_amdgcn_cvt_pk_f32_fp8((int)q1.y, false);
      pf[0] = w0*a.x + w1*b.x;  pf[1] = w0*a.y + w1*b.y;
      a = __builtin_amdgcn_cvt_pk_f32_fp8((int)q0.y, true);
      b = __builtin_amdgcn_cvt_pk_f32_fp8((int)q1.y, true);
      pf[2] = w0*a.x + w1*b.x;  pf[3] = w0*a.y + w1*b.y;
      a = __builtin_amdgcn_cvt_pk_f32_fp8((int)q0.z, false);
      b = __builtin_amdgcn_cvt_pk_f32_fp8((int)q1.z, false);
      pf[4] = w0*a.x + w1*b.x;  pf[5] = w0*a.y + w1*b.y;
      a = __builtin_amdgcn_cvt_pk_f32_fp8((int)q0.z, true);
      b = __builtin_amdgcn_cvt_pk_f32_fp8((int)q1.z, true);
      pf[6] = w0*a.x + w1*b.x;  pf[7] = w0*a.y + w1*b.y;
      a = __builtin_amdgcn_cvt_pk_f32_fp8((int)q0.w, false);
      b = __builtin_amdgcn_cvt_pk_f32_fp8((int)q1.w, false);
      pf[8] = w0*a.x + w1*b.x;  pf[9] = w0*a.y + w1*b.y;
      a = __builtin_amdgcn_cvt_pk_f32_fp8((int)q0.w, true);
      b = __builtin_amdgcn_cvt_pk_f32_fp8((int)q1.w, true);
      pf[10]= w0*a.x + w1*b.x;  pf[11]= w0*a.y + w1*b.y;
    }
#else
    if(PACKED){
      const uint4* pv = packed + vox*2;
      uint4 q0 = pv[0], q1 = pv[1], q2 = pv[2], q3 = pv[3];
      pd = w0*__uint_as_float(q0.x) + w1*__uint_as_float(q2.x);
      pf[0]  = w0*flo(q0.y) + w1*flo(q2.y);  pf[1]  = w0*fhi(q0.y) + w1*fhi(q2.y);
      pf[2]  = w0*flo(q0.z) + w1*flo(q2.z);  pf[3]  = w0*fhi(q0.z) + w1*fhi(q2.z);
      pf[4]  = w0*flo(q0.w) + w1*flo(q2.w);  pf[5]  = w0*fhi(q0.w) + w1*fhi(q2.w);
      pf[6]  = w0*flo(q1.x) + w1*flo(q3.x);  pf[7]  = w0*fhi(q1.x) + w1*fhi(q3.x);
      pf[8]  = w0*flo(q1.y) + w1*flo(q3.y);  pf[9]  = w0*fhi(q1.y) + w1*fhi(q3.y);
      pf[10] = w0*flo(q1.z) + w1*flo(q3.z);  pf[11] = w0*fhi(q1.z) + w1*fhi(q3.z);
    }
#endif
    if(!PACKED){
      pd = w0*density[vox] + w1*density[vox+1];
      const float4* v = (const float4*)(k0 + vox*12);
      float4 a0 = v[0], a1 = v[1], a2 = v[2];
      float4 c0 = v[3], c1 = v[4], c2 = v[5];
      pf[0] = w0*a0.x + w1*c0.x;  pf[1] = w0*a0.y + w1*c0.y;
      pf[2] = w0*a0.z + w1*c0.z;  pf[3] = w0*a0.w + w1*c0.w;
      pf[4] = w0*a1.x + w1*c1.x;  pf[5] = w0*a1.y + w1*c1.y;
      pf[6] = w0*a1.z + w1*c1.z;  pf[7] = w0*a1.w + w1*c1.w;
      pf[8] = w0*a2.x + w1*c2.x;  pf[9] = w0*a2.y + w1*c2.y;
      pf[10]= w0*a2.z + w1*c2.z;  pf[11]= w0*a2.w + w1*c2.w;
    }

    // fp16-packed butterfly: 6 half2 + f32 density -> 14 shfl (was 26)
    f16x2 h[6];
    #pragma unroll
    for(int j = 0; j < 6; ++j) h[j] = __builtin_amdgcn_cvt_pkrtz(pf[2*j], pf[2*j+1]);
    #pragma unroll
    for(int m2 = 1; m2 < 4; m2 <<= 1){
      pd += __shfl_xor(pd, m2);
      #pragma unroll
      for(int j = 0; j < 6; ++j){
        int tt = __shfl_xor(__builtin_bit_cast(int, h[j]), m2);
        h[j] += __builtin_bit_cast(f16x2, tt);
      }
    }
    int R = smp & 31, H = smp >> 5, Rx = R << 4;
    char* b8 = (char*)hA + R*512;
    if(corner == 0){
      bool mm = (mv != 0u);
      float e = __expf(pd + ACT_SHIFT);
      float alpha = 1.f - rsqrtf(1.f + e);   // (1+e)^(-0.5), INTERVAL=0.5
      if(!mm) alpha = 0.f;
      red[smp][3] = alpha;                   // rides out in rgba.w
      unsigned int d[8];
      #pragma unroll
      for(int j = 0; j < 6; ++j) d[j] = packbf((float)h[j][0], (float)h[j][1]);
      d[6] = packbf(x, y);
      d[7] = packbf(z, __sinf(x));           // col 15 = sin(x * 2^0)
      *(uint4*)(b8 + (((H<<8) |  0) ^ Rx)) = make_uint4(d[0],d[1],d[2],d[3]);
      *(uint4*)(b8 + (((H<<8) | 16) ^ Rx)) = make_uint4(d[4],d[5],d[6],d[7]);
    } else if(corner == 1){
      *(uint4*)(b8 + (((H<<8) | 160) ^ Rx)) = make_uint4(0,0,0,0);  // cols 80..87
      *(uint4*)(b8 + (((H<<8) | 176) ^ Rx)) = make_uint4(0,0,0,0);  // cols 88..95
      ray_s[smp] = rid;
    }
    // corners 2,3: gather + butterfly only
  }

  // ---- phase 0b: posemb via double-angle recurrence. role j owns dim j -------
  // cols: sin dim j -> 15+10j..24+10j ; cos dim j -> 45+10j..54+10j (col 15 from 0a)
  {
    int j = tid >> 6, smp = tid & 63;
    int R = smp & 31, H8 = (smp >> 5) << 8, Rx = R << 4;
    char* b8 = (char*)hA + R*512;
    if(j < 3){
      float xv = xyz[3*(blk + smp) + j];
      float s[10], c[10];
      s[0] = __sinf(xv); c[0] = __cosf(xv);
      #pragma unroll
      for(int p = 1; p < 10; ++p){
        float sp = s[p-1], cp = c[p-1];
        s[p] = 2.f*sp*cp;
        c[p] = 1.f - 2.f*sp*sp;
      }
      int sb = 15 + 10*j, cb = 45 + 10*j;
      if(j) *(unsigned short*)(b8 + ((H8 | (sb*2)) ^ Rx)) = f2bf(s[0]);
      #pragma unroll
      for(int p = 0; p < 4; ++p)
        *(unsigned int*)(b8 + ((H8 | ((sb+1+2*p)*2)) ^ Rx)) = packbf(s[1+2*p], s[2+2*p]);
      *(unsigned short*)(b8 + ((H8 | ((sb+9)*2)) ^ Rx)) = f2bf(s[9]);
      *(unsigned short*)(b8 + ((H8 | (cb*2)) ^ Rx)) = f2bf(c[0]);
      #pragma unroll
      for(int p = 0; p < 4; ++p)
        *(unsigned int*)(b8 + ((H8 | ((cb+1+2*p)*2)) ^ Rx)) = packbf(c[1+2*p], c[2+2*p]);
      *(unsigned short*)(b8 + ((H8 | ((cb+9)*2)) ^ Rx)) = f2bf(c[9]);
    } else {
      *(unsigned short*)(b8 + ((H8 | 150) ^ Rx)) = 0;   // col 75
      *(unsigned int*)  (b8 + ((H8 | 152) ^ Rx)) = 0;   // cols 76,77
      *(unsigned int*)  (b8 + ((H8 | 156) ^ Rx)) = 0;   // cols 78,79
    }
  }
  __syncthreads();

  f32x16 acc0, acc1;

  // layer 0 (K=96): wf resident; prefetch layer-1 weights under epilogue
  mfma_layer<96>(hA, wf, b0, wave, acc0, acc1, ln, kh);
  load_wf<8>(wt1 + (wave*32 + ln)*128 + kh*8, wf);
  epilogue(acc0, acc1, hB, wave, ln, kh);
  __syncthreads();

  // layer 1 (K=128)
  mfma_layer<128>(hB, wf, b1, wave, acc0, acc1, ln, kh);
  load_wf<8>(wt2 + (wave*32 + ln)*128 + kh*8, wf);
  epilogue(acc0, acc1, hA, wave, ln, kh);
  __syncthreads();

  // layer 2 (K=128); prefetch head weights under epilogue
  int col = lane & 15, q4 = lane >> 4;
  mfma_layer<128>(hA, wf, b2, wave, acc0, acc1, ln, kh);
  bf16x8 hw[4];
  {
    const unsigned short* wr = wtr + col*128 + q4*8;
    #pragma unroll
    for(int ks = 0; ks < 4; ++ks) hw[ks] = *(const bf16x8*)(wr + ks*32);
  }
  epilogue(acc0, acc1, hB, wave, ln, kh);
  // rayterm prefetch for head (ray_s valid since first sync)
  float rt[4] = {0.f, 0.f, 0.f, 0.f};
  if(col < 3){
    #pragma unroll
    for(int r = 0; r < 4; ++r)
      rt[r] = rayterm3[ray_s[wave*16 + q4*4 + r]*3 + col];
  }
  __syncthreads();

  // rgb head: 16x16x32 MFMA, K=128, 4 m-tiles = 4 waves; acc init = view term
  {
    int mt = wave;
    int s = mt*16 + col;
    int R = s & 31, H = s >> 5, Rx = R << 4;
    const char* s8 = (const char*)hB + R*512;
    f32x4 acc = {rt[0], rt[1], rt[2], rt[3]};
    __builtin_amdgcn_s_setprio(1);
    #pragma unroll
    for(int ks = 0; ks < 4; ++ks){
      bf16x8 af = *(const bf16x8*)(s8 + (((H<<8) | (ks<<6) | (q4<<4)) ^ Rx));
      acc = __builtin_amdgcn_mfma_f32_16x16x32_bf16(af, hw[ks], acc, 0, 0, 0);
    }
    __builtin_amdgcn_s_setprio(0);
    if(col < 3){
      #pragma unroll
      for(int r = 0; r < 4; ++r){
        int sl = mt*16 + q4*4 + r;
        red[sl][col] = __fdividef(1.f, 1.f + __expf(-acc[r]));
      }
    }
  }
  __syncthreads();

  // coalesced rgba store (alpha in .w; composite happens in k_comp2)
  if(tid < SAMP){
    rgba_out[blk + tid] = make_float4(red[tid][0], red[tid][1], red[tid][2], red[tid][3]);
  }
}

// ---------------- per-ray: alpha scan + weighted composite in one pass ---------
__global__ __launch_bounds__(256) void k_comp2(const int* __restrict__ ray_id,
    const float4* __restrict__ rgba, float* __restrict__ out)
{
  int r = blockIdx.x*4 + (threadIdx.x >> 6);   // grid = NRAYS/4 blocks
  int lane = threadIdx.x & 63;
  int lo = 0, hi = M_SAMPLES;
  while(lo < hi){ int mid = (lo+hi) >> 1; if(ray_id[mid] < r) lo = mid+1; else hi = mid; }
  int s = lo;
  int lo2 = s, hi2 = M_SAMPLES;
  while(lo2 < hi2){ int mid = (lo2+hi2) >> 1; if(ray_id[mid] < r+1) lo2 = mid+1; else hi2 = mid; }
  int e = lo2;

  float carry = 1.f;
  float ar = 0.f, ag = 0.f, ab = 0.f;
  for(int base = s; base < e; base += 64){
    int idx = base + lane;
    float4 c = (idx < e) ? rgba[idx] : make_float4(0.f,0.f,0.f,0.f);
    float a = c.w;
    float incl = 1.f - a;
    #pragma unroll
    for(int d2 = 1; d2 < 64; d2 <<= 1){
      float t = __shfl_up(incl, d2);
      if(lane >= d2) incl *= t;
    }
    float excl = __shfl_up(incl, 1);
    if(lane == 0) excl = 1.f;
    float w = carry * excl * a;
    ar += w*c.x; ag += w*c.y; ab += w*c.z;
    carry *= __shfl(incl, 63);
  }
  #pragma unroll
  for(int m2 = 1; m2 < 64; m2 <<= 1){
    ar += __shfl_xor(ar, m2);
    ag += __shfl_xor(ag, m2);
    ab += __shfl_xor(ab, m2);
  }
  if(lane == 0){
    out[3*r+0] = ar + carry;
    out[3*r+1] = ag + carry;
    out[3*r+2] = ab + carry;
  }
}

// ---------------- host ----------------------------------------------------------
extern "C" void kernel_launch(void* const* d_in, const int* in_sizes, int n_in,
                              void* d_out, int out_size, void* d_ws, size_t ws_size,
                              hipStream_t stream)
{
  const float* xyz      = (const float*)d_in[0];
  const int*   ray_id   = (const int*)  d_in[1];
  const float* viewdirs = (const float*)d_in[2];
  const void*  mask     =               d_in[3];
  const float* density  = (const float*)d_in[4];
  const float* k0       = (const float*)d_in[5];
  const float* W0 = (const float*)d_in[6];  const float* b0 = (const float*)d_in[7];
  const float* W1 = (const float*)d_in[8];  const float* b1 = (const float*)d_in[9];
  const float* W2 = (const float*)d_in[10]; const float* b2 = (const float*)d_in[11];
  const float* Wr = (const float*)d_in[12]; const float* br = (const float*)d_in[13];
  float* out = (float*)d_out;

  char* ws = (char*)d_ws;
  size_t off = 0;
  auto take = [&](size_t nbytes) -> void* {
    void* p = ws + off;
    off = (off + nbytes + 255) & ~(size_t)255;
    return p;
  };
  int*            flag     = (int*)           take(4);
  unsigned short* wt0      = (unsigned short*)take(128*96*2);
  unsigned short* wt1      = (unsigned short*)take(128*128*2);
  unsigned short* wt2      = (unsigned short*)take(128*128*2);
  unsigned short* wtr      = (unsigned short*)take(16*128*2);
  float*          rayterm3 = (float*)         take((size_t)NRAYS*3*4);
  float4*         rgba_ws  = (float4*)        take((size_t)M_SAMPLES*16);
#ifdef HAVE_FP8
  uint4*          packed   = (uint4*)         take((size_t)NVOX*16);
#else
  uint4*          packed   = (uint4*)         take((size_t)NVOX*32);
#endif
  bool use_packed = (ws_size >= off);

  k_prep<<<NB_REPACK + 1 + NB_W + NB_RT, 256, 0, stream>>>(
      density, k0, packed, (const unsigned int*)mask, flag,
      W0, W1, W2, Wr, br, wt0, wt1, wt2, wtr, viewdirs, rayterm3);
  if(use_packed){
    k_mlp<1><<<M_SAMPLES/SAMP, 256, 0, stream>>>(xyz, packed, density, k0, mask, flag,
                                                 ray_id, wt0, wt1, wt2, wtr,
                                                 b0, b1, b2, rayterm3, rgba_ws);
  } else {
    k_mlp<0><<<M_SAMPLES/SAMP, 256, 0, stream>>>(xyz, packed, density, k0, mask, flag,
                                                 ray_id, wt0, wt1, wt2, wtr,
                                                 b0, b1, b2, rayterm3, rgba_ws);
  }
  k_comp2<<<NRAYS/4, 256, 0, stream>>>(ray_id, rgba_ws, out);
}